// Round 1
// baseline (2200.664 us; speedup 1.0000x reference)
//
#include <hip/hip_runtime.h>

#define NN 4096

// ws layout (float offsets)
#define OFF_G   0
#define OFF_S   4096
#define OFF_GS  (OFF_S + 64*4096)        // raw-k 32-row group sums [64 heads][128 groups][64]
#define OFF_KP  (OFF_GS + 64*128*64)     // exclusive group prefixes [64][128][64]
#define OFF_W   OFF_GS                   // W = G@S per head [64][64][64] — ALIASES gs (dead after kC)

// ---------------- Kernel A: G = P^T P  (P is [64,64]) ----------------
__global__ void kA_gram(const float* __restrict__ P, float* __restrict__ G) {
    int i = blockIdx.x;      // 0..63
    int j = threadIdx.x;     // 0..63
    float acc = 0.f;
    for (int m = 0; m < 64; ++m)
        acc += P[m*64 + i] * P[m*64 + j];
    G[i*64 + j] = acc;
}

// ------- Kernel B: per (head, 256-row chunk): S += K^T V + raw-k 32-row group sums -------
// Lane j holds S column j in registers (Scol[64]); k rows arrive as LDS broadcasts.
// Waves are independent until the tail (each wave stages/reads only its own 16 rows).
__launch_bounds__(256)
__global__ void kB(const float* __restrict__ k, const float* __restrict__ v,
                   float* __restrict__ S, float* __restrict__ gs) {
    __shared__ __align__(16) float kt[64*64];   // 16 KB, no padding (broadcast + lane-consecutive only)
    __shared__ __align__(16) float vt[64*64];   // 16 KB
    __shared__ float gsb[16*64];                // 16 half-group (16-row) k sums

    int t = threadIdx.x, w = t >> 6, lane = t & 63;
    int head = blockIdx.y, chunk = blockIdx.x;
    long base = ((long)head*NN + (long)chunk*256) * 64;

    float Scol[64];
#pragma unroll
    for (int i = 0; i < 64; ++i) Scol[i] = 0.f;

    for (int s = 0; s < 4; ++s) {
        // stage own 16 rows of k and v (wave-private slice, no barrier needed)
        const float4* kg4 = (const float4*)(k + base + (long)s*4096 + w*1024);
        const float4* vg4 = (const float4*)(v + base + (long)s*4096 + w*1024);
        float4* kl4 = (float4*)&kt[w*1024];
        float4* vl4 = (float4*)&vt[w*1024];
#pragma unroll
        for (int c = 0; c < 4; ++c) {
            kl4[c*64 + lane] = kg4[c*64 + lane];
            vl4[c*64 + lane] = vg4[c*64 + lane];
        }

        // 16-row k half-sum for this wave (feeds the 32-row group sums)
        float hs = 0.f;
#pragma unroll
        for (int r = 0; r < 16; ++r) hs += kt[(w*16 + r)*64 + lane];
        gsb[(s*4 + w)*64 + lane] = hs;

        // S accumulation: Scol[i] += k[r][i] * v[r][lane]
#pragma unroll
        for (int r = 0; r < 16; ++r) {
            float vv = vt[(w*16 + r)*64 + lane];
            const float4* krow = (const float4*)&kt[(w*16 + r)*64];
#pragma unroll
            for (int kq = 0; kq < 16; ++kq) {
                float4 kx = krow[kq];           // wave-uniform broadcast read
                Scol[4*kq+0] += kx.x * vv;
                Scol[4*kq+1] += kx.y * vv;
                Scol[4*kq+2] += kx.z * vv;
                Scol[4*kq+3] += kx.w * vv;
            }
        }
    }
    __syncthreads();

    // gs: combine 16-row halves into 32-row groups (8 groups per chunk)
#pragma unroll
    for (int e = t; e < 512; e += 256) {
        int g = e >> 6, c = e & 63;
        gs[((long)head*128 + chunk*8 + g)*64 + c] = gsb[(2*g)*64 + c] + gsb[(2*g+1)*64 + c];
    }

    // 4-phase cross-wave reduction of Scol into kt, then atomics
    if (w == 0) {
#pragma unroll
        for (int i = 0; i < 64; ++i) kt[i*64 + lane] = Scol[i];
    }
    __syncthreads();
    if (w == 1) {
#pragma unroll
        for (int i = 0; i < 64; ++i) kt[i*64 + lane] += Scol[i];
    }
    __syncthreads();
    if (w == 2) {
#pragma unroll
        for (int i = 0; i < 64; ++i) kt[i*64 + lane] += Scol[i];
    }
    __syncthreads();
    if (w == 3) {
#pragma unroll
        for (int i = 0; i < 64; ++i) kt[i*64 + lane] += Scol[i];
    }
    __syncthreads();
#pragma unroll
    for (int e = t; e < 4096; e += 256)
        atomicAdd(&S[head*4096 + e], kt[e]);
}

// ------- Kernel C: per head: exclusive scan of group sums -> kpre -------
__launch_bounds__(256)
__global__ void kC(const float* __restrict__ gs, float* __restrict__ kpre) {
    __shared__ __align__(16) float gL[128*68];
    int t = threadIdx.x;
    int head = blockIdx.x;

    const float4* gs4 = (const float4*)(gs + (long)head*128*64);
    float4* gL4 = (float4*)gL;
#pragma unroll
    for (int i = 0; i < 8; ++i) {
        int f = t + 256*i;              // 0..2047
        int r = f >> 4, c = f & 15;
        gL4[r*17 + c] = gs4[f];
    }
    __syncthreads();

    if (t < 64) {
        float run = 0.f;
        for (int g = 0; g < 128; ++g) {
            kpre[((long)head*128 + g)*64 + t] = run;
            run += gL[g*68 + t];
        }
    }
}

// ------- Kernel W: per head: W = G @ S  (64x64 @ 64x64) -------
// grid (64 rows, 64 heads), 64 threads = one output column each.
// Runs after kC; writes into the (dead) gs region.
__global__ void kW(const float* __restrict__ G, const float* __restrict__ S,
                   float* __restrict__ W) {
    int i = blockIdx.x;       // output row
    int head = blockIdx.y;
    int j = threadIdx.x;      // output col
    const float* Sh = S + (long)head*4096;
    float acc = 0.f;
#pragma unroll
    for (int m = 0; m < 64; ++m)
        acc = fmaf(G[i*64 + m], Sh[m*64 + j], acc);   // G[i][m] wave-uniform broadcast
    W[(long)head*4096 + i*64 + j] = acc;
}

// ------- Kernel D (fused): acc = q@G (denominator), o16 = q@W (numerator) -------
// One broadcast pass over q feeds BOTH matmuls: each ds_read_b128 -> 8 fmaf.
// No bufB, no k restage through LDS (cumsum reads k straight from global).
// Wave-independent; NO __syncthreads anywhere.
__launch_bounds__(256, 4)
__global__ void kD(const float* __restrict__ q, const float* __restrict__ k,
                   const float* __restrict__ G, const float* __restrict__ W,
                   const float* __restrict__ kpre, float* __restrict__ out) {
    __shared__ __align__(16) float bufA[64*64];   // q rows (per-wave 16-row slices), 16 KB

    int t = threadIdx.x, w = t >> 6, lane = t & 63;
    int head = blockIdx.y, tile = blockIdx.x;     // 64 tiles of 64 rows
    long rowbase = (long)head*NN + (long)tile*64; // global row index of tile start

    // ---- stage own 16 q rows (wave-private slice) ----
    {
        const float4* qg4 = (const float4*)(q + (rowbase + w*16)*64);
        float4* A4 = (float4*)&bufA[w*1024];
#pragma unroll
        for (int c = 0; c < 4; ++c) A4[c*64 + lane] = qg4[c*64 + lane];
    }

    float acc[16], o16[16];
#pragma unroll
    for (int r = 0; r < 16; ++r) { acc[r] = 0.f; o16[r] = 0.f; }

    const float* Wh = W + (long)head*4096;

    // ---- fused matmul: acc[r] = (q@G)[r][lane], o16[r] = (q@W)[r][lane] ----
#pragma unroll
    for (int h = 0; h < 2; ++h) {
        float Gc[32], Wc[32];
#pragma unroll
        for (int kk = 0; kk < 32; ++kk) {
            Gc[kk] = G[(h*32 + kk)*64 + lane];
            Wc[kk] = Wh[(h*32 + kk)*64 + lane];
        }
#pragma unroll
        for (int kq = 0; kq < 8; ++kq) {
#pragma unroll
            for (int r = 0; r < 16; ++r) {
                float4 q4 = *(const float4*)&bufA[(w*16 + r)*64 + h*32 + kq*4]; // broadcast
                acc[r] = fmaf(q4.x, Gc[kq*4+0], acc[r]);
                acc[r] = fmaf(q4.y, Gc[kq*4+1], acc[r]);
                acc[r] = fmaf(q4.z, Gc[kq*4+2], acc[r]);
                acc[r] = fmaf(q4.w, Gc[kq*4+3], acc[r]);
                o16[r] = fmaf(q4.x, Wc[kq*4+0], o16[r]);
                o16[r] = fmaf(q4.y, Wc[kq*4+1], o16[r]);
                o16[r] = fmaf(q4.z, Wc[kq*4+2], o16[r]);
                o16[r] = fmaf(q4.w, Wc[kq*4+3], o16[r]);
            }
        }
    }

    // ---- group prefix: kpre + (odd waves) top-up from global k ----
    float pre = kpre[((long)head*128 + tile*2 + (w >> 1))*64 + lane];
    if (w & 1) {
        const float* kp = k + (rowbase + (w-1)*16)*64;
#pragma unroll
        for (int r = 0; r < 16; ++r) pre += kp[r*64 + lane];
    }

    // ---- cumsum (k direct from global, coalesced) + denominators ----
    const float* kown = k + (rowbase + w*16)*64;
    float dinv[16];
#pragma unroll
    for (int r = 0; r < 16; ++r) {
        pre += kown[r*64 + lane];                 // kcum[row][lane]
        float p = acc[r] * pre;                   // qg . kcum, partial per lane
#pragma unroll
        for (int o = 32; o; o >>= 1) p += __shfl_xor(p, o, 64);
        dinv[r] = __builtin_amdgcn_rcpf(p);
    }

    // ---- store ----
#pragma unroll
    for (int r = 0; r < 16; ++r)
        out[(rowbase + w*16 + r)*64 + lane] = o16[r] * dinv[r];
}

extern "C" void kernel_launch(void* const* d_in, const int* in_sizes, int n_in,
                              void* d_out, int out_size, void* d_ws, size_t ws_size,
                              hipStream_t stream) {
    (void)in_sizes; (void)n_in; (void)out_size; (void)ws_size;
    const float* q = (const float*)d_in[0];
    const float* k = (const float*)d_in[1];
    const float* v = (const float*)d_in[2];
    const float* P = (const float*)d_in[3];
    float* out = (float*)d_out;
    float* ws  = (float*)d_ws;

    float* G    = ws + OFF_G;
    float* S    = ws + OFF_S;
    float* gs   = ws + OFF_GS;
    float* kpre = ws + OFF_KP;
    float* W    = ws + OFF_W;     // aliases gs (dead after kC)

    hipMemsetAsync(S, 0, (size_t)64*4096*sizeof(float), stream);
    kA_gram<<<64, 64, 0, stream>>>(P, G);
    kB<<<dim3(16, 64), 256, 0, stream>>>(k, v, S, gs);
    kC<<<64, 256, 0, stream>>>(gs, kpre);
    kW<<<dim3(64, 64), 64, 0, stream>>>(G, S, W);
    kD<<<dim3(64, 64), 256, 0, stream>>>(q, k, G, W, kpre, out);
}

// Round 2
// 1825.443 us; speedup vs baseline: 1.2056x; 1.2056x over previous
//
#include <hip/hip_runtime.h>

#define NN 4096

// ws layout (float offsets)
#define OFF_G   0
#define OFF_S   4096
#define OFF_GS  (OFF_S + 64*4096)        // raw-k 32-row group sums [64 heads][128 groups][64]
#define OFF_KP  (OFF_GS + 64*128*64)     // exclusive group prefixes [64][128][64]
#define OFF_W   OFF_GS                   // W = G@S per head [64][64][64] — ALIASES gs (dead after kC)

// ---------------- Kernel A: G = P^T P  (P is [64,64]) ----------------
__global__ void kA_gram(const float* __restrict__ P, float* __restrict__ G) {
    int i = blockIdx.x;      // 0..63
    int j = threadIdx.x;     // 0..63
    float acc = 0.f;
    for (int m = 0; m < 64; ++m)
        acc += P[m*64 + i] * P[m*64 + j];
    G[i*64 + j] = acc;
}

// ------- Kernel B: per (head, 256-row chunk): S += K^T V + raw-k 32-row group sums -------
__launch_bounds__(256)
__global__ void kB(const float* __restrict__ k, const float* __restrict__ v,
                   float* __restrict__ S, float* __restrict__ gs) {
    __shared__ __align__(16) float kt[64*64];   // 16 KB
    __shared__ __align__(16) float vt[64*64];   // 16 KB
    __shared__ float gsb[16*64];                // 16 half-group (16-row) k sums

    int t = threadIdx.x, w = t >> 6, lane = t & 63;
    int head = blockIdx.y, chunk = blockIdx.x;
    long base = ((long)head*NN + (long)chunk*256) * 64;

    float Scol[64];
#pragma unroll
    for (int i = 0; i < 64; ++i) Scol[i] = 0.f;

    for (int s = 0; s < 4; ++s) {
        // stage own 16 rows of k and v (wave-private slice, no barrier needed)
        const float4* kg4 = (const float4*)(k + base + (long)s*4096 + w*1024);
        const float4* vg4 = (const float4*)(v + base + (long)s*4096 + w*1024);
        float4* kl4 = (float4*)&kt[w*1024];
        float4* vl4 = (float4*)&vt[w*1024];
#pragma unroll
        for (int c = 0; c < 4; ++c) {
            kl4[c*64 + lane] = kg4[c*64 + lane];
            vl4[c*64 + lane] = vg4[c*64 + lane];
        }

        // 16-row k half-sum for this wave (feeds the 32-row group sums)
        float hs = 0.f;
#pragma unroll
        for (int r = 0; r < 16; ++r) hs += kt[(w*16 + r)*64 + lane];
        gsb[(s*4 + w)*64 + lane] = hs;

        // S accumulation: Scol[i] += k[r][i] * v[r][lane]
#pragma unroll
        for (int r = 0; r < 16; ++r) {
            float vv = vt[(w*16 + r)*64 + lane];
            const float4* krow = (const float4*)&kt[(w*16 + r)*64];
#pragma unroll
            for (int kq = 0; kq < 16; ++kq) {
                float4 kx = krow[kq];           // wave-uniform broadcast read
                Scol[4*kq+0] += kx.x * vv;
                Scol[4*kq+1] += kx.y * vv;
                Scol[4*kq+2] += kx.z * vv;
                Scol[4*kq+3] += kx.w * vv;
            }
        }
    }
    __syncthreads();

    // gs: combine 16-row halves into 32-row groups (8 groups per chunk)
#pragma unroll
    for (int e = t; e < 512; e += 256) {
        int g = e >> 6, c = e & 63;
        gs[((long)head*128 + chunk*8 + g)*64 + c] = gsb[(2*g)*64 + c] + gsb[(2*g+1)*64 + c];
    }

    // 4-phase cross-wave reduction of Scol into kt, then atomics
    if (w == 0) {
#pragma unroll
        for (int i = 0; i < 64; ++i) kt[i*64 + lane] = Scol[i];
    }
    __syncthreads();
    if (w == 1) {
#pragma unroll
        for (int i = 0; i < 64; ++i) kt[i*64 + lane] += Scol[i];
    }
    __syncthreads();
    if (w == 2) {
#pragma unroll
        for (int i = 0; i < 64; ++i) kt[i*64 + lane] += Scol[i];
    }
    __syncthreads();
    if (w == 3) {
#pragma unroll
        for (int i = 0; i < 64; ++i) kt[i*64 + lane] += Scol[i];
    }
    __syncthreads();
#pragma unroll
    for (int e = t; e < 4096; e += 256)
        atomicAdd(&S[head*4096 + e], kt[e]);
}

// ------- Kernel C: per head: exclusive scan of group sums -> kpre -------
__launch_bounds__(256)
__global__ void kC(const float* __restrict__ gs, float* __restrict__ kpre) {
    __shared__ __align__(16) float gL[128*68];
    int t = threadIdx.x;
    int head = blockIdx.x;

    const float4* gs4 = (const float4*)(gs + (long)head*128*64);
    float4* gL4 = (float4*)gL;
#pragma unroll
    for (int i = 0; i < 8; ++i) {
        int f = t + 256*i;              // 0..2047
        int r = f >> 4, c = f & 15;
        gL4[r*17 + c] = gs4[f];
    }
    __syncthreads();

    if (t < 64) {
        float run = 0.f;
        for (int g = 0; g < 128; ++g) {
            kpre[((long)head*128 + g)*64 + t] = run;
            run += gL[g*68 + t];
        }
    }
}

// ------- Kernel W: per head: W = G @ S  (64x64 @ 64x64) -------
// grid (64 rows, 64 heads), 64 threads = one output column each.
// Runs after kC; writes into the (dead) gs region.
__global__ void kW(const float* __restrict__ G, const float* __restrict__ S,
                   float* __restrict__ W) {
    int i = blockIdx.x;       // output row
    int head = blockIdx.y;
    int j = threadIdx.x;      // output col
    const float* Sh = S + (long)head*4096;
    float acc = 0.f;
#pragma unroll
    for (int m = 0; m < 64; ++m)
        acc = fmaf(G[i*64 + m], Sh[m*64 + j], acc);   // G[i][m] wave-uniform broadcast
    W[(long)head*4096 + i*64 + j] = acc;
}

// ------- Kernel D (fused): acc = q@G (denominator), o16 = q@W (numerator) -------
// One broadcast pass over q feeds BOTH matmuls: each ds_read_b128 -> 8 fmaf.
// Column dim chunked at 16 (live set ~72 regs: Gc16+Wc16+acc16+o16) to stay
// spill-free — round-1 post-mortem: 32-chunks + launch_bounds(256,4) spilled
// ~4 KB/thread to scratch (WRITE_SIZE 4.4 GB, 20x regression).
// Wave-independent; NO __syncthreads anywhere.
__launch_bounds__(256)
__global__ void kD(const float* __restrict__ q, const float* __restrict__ k,
                   const float* __restrict__ G, const float* __restrict__ W,
                   const float* __restrict__ kpre, float* __restrict__ out) {
    __shared__ __align__(16) float bufA[64*64];   // q rows (per-wave 16-row slices), 16 KB

    int t = threadIdx.x, w = t >> 6, lane = t & 63;
    int head = blockIdx.y, tile = blockIdx.x;     // 64 tiles of 64 rows
    long rowbase = (long)head*NN + (long)tile*64; // global row index of tile start

    // ---- stage own 16 q rows (wave-private slice) ----
    {
        const float4* qg4 = (const float4*)(q + (rowbase + w*16)*64);
        float4* A4 = (float4*)&bufA[w*1024];
#pragma unroll
        for (int c = 0; c < 4; ++c) A4[c*64 + lane] = qg4[c*64 + lane];
    }

    float acc[16], o16[16];
#pragma unroll
    for (int r = 0; r < 16; ++r) { acc[r] = 0.f; o16[r] = 0.f; }

    const float* Wh = W + (long)head*4096;

    // ---- fused matmul: acc[r] = (q@G)[r][lane], o16[r] = (q@W)[r][lane] ----
    // 4 chunks of 16 columns: live set stays ~72 VGPRs.
#pragma unroll
    for (int h = 0; h < 4; ++h) {
        float Gc[16], Wc[16];
#pragma unroll
        for (int kk = 0; kk < 16; ++kk) {
            Gc[kk] = G[(h*16 + kk)*64 + lane];
            Wc[kk] = Wh[(h*16 + kk)*64 + lane];
        }
#pragma unroll
        for (int kq = 0; kq < 4; ++kq) {
#pragma unroll
            for (int r = 0; r < 16; ++r) {
                float4 q4 = *(const float4*)&bufA[(w*16 + r)*64 + h*16 + kq*4]; // broadcast
                acc[r] = fmaf(q4.x, Gc[kq*4+0], acc[r]);
                acc[r] = fmaf(q4.y, Gc[kq*4+1], acc[r]);
                acc[r] = fmaf(q4.z, Gc[kq*4+2], acc[r]);
                acc[r] = fmaf(q4.w, Gc[kq*4+3], acc[r]);
                o16[r] = fmaf(q4.x, Wc[kq*4+0], o16[r]);
                o16[r] = fmaf(q4.y, Wc[kq*4+1], o16[r]);
                o16[r] = fmaf(q4.z, Wc[kq*4+2], o16[r]);
                o16[r] = fmaf(q4.w, Wc[kq*4+3], o16[r]);
            }
        }
    }

    // ---- group prefix: kpre + (odd waves) top-up from global k ----
    float pre = kpre[((long)head*128 + tile*2 + (w >> 1))*64 + lane];
    if (w & 1) {
        const float* kp = k + (rowbase + (w-1)*16)*64;
#pragma unroll
        for (int r = 0; r < 16; ++r) pre += kp[r*64 + lane];
    }

    // ---- cumsum (k direct from global, coalesced) + denominators ----
    const float* kown = k + (rowbase + w*16)*64;
    float dinv[16];
#pragma unroll
    for (int r = 0; r < 16; ++r) {
        pre += kown[r*64 + lane];                 // kcum[row][lane]
        float p = acc[r] * pre;                   // qg . kcum, partial per lane
#pragma unroll
        for (int o = 32; o; o >>= 1) p += __shfl_xor(p, o, 64);
        dinv[r] = __builtin_amdgcn_rcpf(p);
    }

    // ---- store ----
#pragma unroll
    for (int r = 0; r < 16; ++r)
        out[(rowbase + w*16 + r)*64 + lane] = o16[r] * dinv[r];
}

extern "C" void kernel_launch(void* const* d_in, const int* in_sizes, int n_in,
                              void* d_out, int out_size, void* d_ws, size_t ws_size,
                              hipStream_t stream) {
    (void)in_sizes; (void)n_in; (void)out_size; (void)ws_size;
    const float* q = (const float*)d_in[0];
    const float* k = (const float*)d_in[1];
    const float* v = (const float*)d_in[2];
    const float* P = (const float*)d_in[3];
    float* out = (float*)d_out;
    float* ws  = (float*)d_ws;

    float* G    = ws + OFF_G;
    float* S    = ws + OFF_S;
    float* gs   = ws + OFF_GS;
    float* kpre = ws + OFF_KP;
    float* W    = ws + OFF_W;     // aliases gs (dead after kC)

    hipMemsetAsync(S, 0, (size_t)64*4096*sizeof(float), stream);
    kA_gram<<<64, 64, 0, stream>>>(P, G);
    kB<<<dim3(16, 64), 256, 0, stream>>>(k, v, S, gs);
    kC<<<64, 256, 0, stream>>>(gs, kpre);
    kW<<<dim3(64, 64), 64, 0, stream>>>(G, S, W);
    kD<<<dim3(64, 64), 256, 0, stream>>>(q, k, G, W, kpre, out);
}

// Round 3
// 328.103 us; speedup vs baseline: 6.7072x; 5.5636x over previous
//
#include <hip/hip_runtime.h>

#define NN 4096

// ws layout (float offsets)
#define OFF_G   0
#define OFF_S   4096
#define OFF_GS  (OFF_S + 64*4096)        // raw-k 32-row group sums [64 heads][128 groups][64]
#define OFF_KP  (OFF_GS + 64*128*64)     // exclusive group prefixes [64][128][64]
#define OFF_W   OFF_GS                   // W = G@S per head [64][64][64] — ALIASES gs (dead after kC)

// ---------------- Kernel A: G = P^T P  (P is [64,64]) ----------------
__global__ void kA_gram(const float* __restrict__ P, float* __restrict__ G) {
    int i = blockIdx.x;      // 0..63
    int j = threadIdx.x;     // 0..63
    float acc = 0.f;
    for (int m = 0; m < 64; ++m)
        acc += P[m*64 + i] * P[m*64 + j];
    G[i*64 + j] = acc;
}

// ------- Kernel B: per (head, 256-row chunk): S += K^T V + raw-k 32-row group sums -------
__launch_bounds__(256)
__global__ void kB(const float* __restrict__ k, const float* __restrict__ v,
                   float* __restrict__ S, float* __restrict__ gs) {
    __shared__ __align__(16) float kt[64*64];   // 16 KB
    __shared__ __align__(16) float vt[64*64];   // 16 KB
    __shared__ float gsb[16*64];                // 16 half-group (16-row) k sums

    int t = threadIdx.x, w = t >> 6, lane = t & 63;
    int head = blockIdx.y, chunk = blockIdx.x;
    long base = ((long)head*NN + (long)chunk*256) * 64;

    float Scol[64];
#pragma unroll
    for (int i = 0; i < 64; ++i) Scol[i] = 0.f;

    for (int s = 0; s < 4; ++s) {
        // stage own 16 rows of k and v (wave-private slice, no barrier needed)
        const float4* kg4 = (const float4*)(k + base + (long)s*4096 + w*1024);
        const float4* vg4 = (const float4*)(v + base + (long)s*4096 + w*1024);
        float4* kl4 = (float4*)&kt[w*1024];
        float4* vl4 = (float4*)&vt[w*1024];
#pragma unroll
        for (int c = 0; c < 4; ++c) {
            kl4[c*64 + lane] = kg4[c*64 + lane];
            vl4[c*64 + lane] = vg4[c*64 + lane];
        }

        // 16-row k half-sum for this wave (feeds the 32-row group sums)
        float hs = 0.f;
#pragma unroll
        for (int r = 0; r < 16; ++r) hs += kt[(w*16 + r)*64 + lane];
        gsb[(s*4 + w)*64 + lane] = hs;

        // S accumulation: Scol[i] += k[r][i] * v[r][lane]
#pragma unroll
        for (int r = 0; r < 16; ++r) {
            float vv = vt[(w*16 + r)*64 + lane];
            const float4* krow = (const float4*)&kt[(w*16 + r)*64];
#pragma unroll
            for (int kq = 0; kq < 16; ++kq) {
                float4 kx = krow[kq];           // wave-uniform broadcast read
                Scol[4*kq+0] += kx.x * vv;
                Scol[4*kq+1] += kx.y * vv;
                Scol[4*kq+2] += kx.z * vv;
                Scol[4*kq+3] += kx.w * vv;
            }
        }
    }
    __syncthreads();

    // gs: combine 16-row halves into 32-row groups (8 groups per chunk)
#pragma unroll
    for (int e = t; e < 512; e += 256) {
        int g = e >> 6, c = e & 63;
        gs[((long)head*128 + chunk*8 + g)*64 + c] = gsb[(2*g)*64 + c] + gsb[(2*g+1)*64 + c];
    }

    // 4-phase cross-wave reduction of Scol into kt, then atomics
    if (w == 0) {
#pragma unroll
        for (int i = 0; i < 64; ++i) kt[i*64 + lane] = Scol[i];
    }
    __syncthreads();
    if (w == 1) {
#pragma unroll
        for (int i = 0; i < 64; ++i) kt[i*64 + lane] += Scol[i];
    }
    __syncthreads();
    if (w == 2) {
#pragma unroll
        for (int i = 0; i < 64; ++i) kt[i*64 + lane] += Scol[i];
    }
    __syncthreads();
    if (w == 3) {
#pragma unroll
        for (int i = 0; i < 64; ++i) kt[i*64 + lane] += Scol[i];
    }
    __syncthreads();
#pragma unroll
    for (int e = t; e < 4096; e += 256)
        atomicAdd(&S[head*4096 + e], kt[e]);
}

// ------- Kernel C: per head: exclusive scan of group sums -> kpre -------
__launch_bounds__(256)
__global__ void kC(const float* __restrict__ gs, float* __restrict__ kpre) {
    __shared__ __align__(16) float gL[128*68];
    int t = threadIdx.x;
    int head = blockIdx.x;

    const float4* gs4 = (const float4*)(gs + (long)head*128*64);
    float4* gL4 = (float4*)gL;
#pragma unroll
    for (int i = 0; i < 8; ++i) {
        int f = t + 256*i;              // 0..2047
        int r = f >> 4, c = f & 15;
        gL4[r*17 + c] = gs4[f];
    }
    __syncthreads();

    if (t < 64) {
        float run = 0.f;
        for (int g = 0; g < 128; ++g) {
            kpre[((long)head*128 + g)*64 + t] = run;
            run += gL[g*68 + t];
        }
    }
}

// ------- Kernel W: per head: W = G @ S  (64x64 @ 64x64) -------
// Runs after kC; writes into the (dead) gs region.
__global__ void kW(const float* __restrict__ G, const float* __restrict__ S,
                   float* __restrict__ W) {
    int i = blockIdx.x;       // output row
    int head = blockIdx.y;
    int j = threadIdx.x;      // output col
    const float* Sh = S + (long)head*4096;
    float acc = 0.f;
#pragma unroll
    for (int m = 0; m < 64; ++m)
        acc = fmaf(G[i*64 + m], Sh[m*64 + j], acc);   // G[i][m] wave-uniform broadcast
    W[(long)head*4096 + i*64 + j] = acc;
}

// ------- Kernel D (fused, scheduler-fenced): acc = q@G, o8 = q@W -------
// Round-1/2 post-mortem: fully-unrolled fused loop let the list scheduler
// hoist ALL B-loads + ds_reads into one window -> ~2.6 KB/thread scratch
// spill (WRITE_SIZE 2.8 GB). Fixes here:
//   (a) #pragma unroll 1 on the chunk loop (real loop = hoist fence),
//   (b) sched_barrier(0) at each chunk top (blocks software pipelining),
//   (c) 8 waves x 8 rows (512-thr block): live set ~70 VGPR, 2x TLP.
// Wave-independent; NO __syncthreads anywhere.
__launch_bounds__(512)
__global__ void kD(const float* __restrict__ q, const float* __restrict__ k,
                   const float* __restrict__ G, const float* __restrict__ W,
                   const float* __restrict__ kpre, float* __restrict__ out) {
    __shared__ __align__(16) float bufA[64*64];   // q rows (per-wave 8-row slices), 16 KB

    int t = threadIdx.x, w = t >> 6, lane = t & 63;   // w: 0..7
    int head = blockIdx.y, tile = blockIdx.x;         // 64 tiles of 64 rows
    long rowbase = (long)head*NN + (long)tile*64;     // global row index of tile start

    // ---- stage own 8 q rows (wave-private slice, no barrier needed) ----
    {
        const float4* qg4 = (const float4*)(q + (rowbase + w*8)*64);
        float4* A4 = (float4*)&bufA[w*512];
#pragma unroll
        for (int c = 0; c < 2; ++c) A4[c*64 + lane] = qg4[c*64 + lane];
    }

    float acc[8], o8[8];
#pragma unroll
    for (int r = 0; r < 8; ++r) { acc[r] = 0.f; o8[r] = 0.f; }

    const float* Wh = W + (long)head*4096;

    // ---- fused matmul, 4 fenced chunks of 16 columns ----
#pragma unroll 1
    for (int h = 0; h < 4; ++h) {
        __builtin_amdgcn_sched_barrier(0);   // nothing crosses a chunk boundary
        float Gc[16], Wc[16];
#pragma unroll
        for (int kk = 0; kk < 16; ++kk) {
            Gc[kk] = G[(h*16 + kk)*64 + lane];
            Wc[kk] = Wh[(h*16 + kk)*64 + lane];
        }
#pragma unroll
        for (int kq = 0; kq < 4; ++kq) {
#pragma unroll
            for (int r = 0; r < 8; ++r) {
                float4 q4 = *(const float4*)&bufA[(w*8 + r)*64 + h*16 + kq*4]; // broadcast
                acc[r] = fmaf(q4.x, Gc[kq*4+0], acc[r]);
                acc[r] = fmaf(q4.y, Gc[kq*4+1], acc[r]);
                acc[r] = fmaf(q4.z, Gc[kq*4+2], acc[r]);
                acc[r] = fmaf(q4.w, Gc[kq*4+3], acc[r]);
                o8[r]  = fmaf(q4.x, Wc[kq*4+0], o8[r]);
                o8[r]  = fmaf(q4.y, Wc[kq*4+1], o8[r]);
                o8[r]  = fmaf(q4.z, Wc[kq*4+2], o8[r]);
                o8[r]  = fmaf(q4.w, Wc[kq*4+3], o8[r]);
            }
        }
    }
    __builtin_amdgcn_sched_barrier(0);

    // ---- group prefix: kpre (32-row groups) + top-up from global k ----
    // wave rows = [w*8, w*8+8); group = tile*2 + (w>>2); top-up = (w&3)*8 rows
    float pre = kpre[((long)head*128 + tile*2 + (w >> 2))*64 + lane];
    {
        int tu = (w & 3) * 8;
        const float* kg = k + (rowbase + (w >> 2)*32)*64;
        for (int r = 0; r < tu; ++r) pre += kg[r*64 + lane];
    }

    // ---- cumsum (k direct from global, coalesced) + denominators ----
    const float* kown = k + (rowbase + w*8)*64;
    float dinv[8];
#pragma unroll
    for (int r = 0; r < 8; ++r) {
        pre += kown[r*64 + lane];                 // kcum[row][lane]
        float p = acc[r] * pre;                   // qg . kcum, partial per lane
#pragma unroll
        for (int o = 32; o; o >>= 1) p += __shfl_xor(p, o, 64);
        dinv[r] = __builtin_amdgcn_rcpf(p);
    }

    // ---- store ----
#pragma unroll
    for (int r = 0; r < 8; ++r)
        out[(rowbase + w*8 + r)*64 + lane] = o8[r] * dinv[r];
}

extern "C" void kernel_launch(void* const* d_in, const int* in_sizes, int n_in,
                              void* d_out, int out_size, void* d_ws, size_t ws_size,
                              hipStream_t stream) {
    (void)in_sizes; (void)n_in; (void)out_size; (void)ws_size;
    const float* q = (const float*)d_in[0];
    const float* k = (const float*)d_in[1];
    const float* v = (const float*)d_in[2];
    const float* P = (const float*)d_in[3];
    float* out = (float*)d_out;
    float* ws  = (float*)d_ws;

    float* G    = ws + OFF_G;
    float* S    = ws + OFF_S;
    float* gs   = ws + OFF_GS;
    float* kpre = ws + OFF_KP;
    float* W    = ws + OFF_W;     // aliases gs (dead after kC)

    hipMemsetAsync(S, 0, (size_t)64*4096*sizeof(float), stream);
    kA_gram<<<64, 64, 0, stream>>>(P, G);
    kB<<<dim3(16, 64), 256, 0, stream>>>(k, v, S, gs);
    kC<<<64, 256, 0, stream>>>(gs, kpre);
    kW<<<dim3(64, 64), 64, 0, stream>>>(G, S, W);
    kD<<<dim3(64, 64), 512, 0, stream>>>(q, k, G, W, kpre, out);
}

// Round 4
// 322.840 us; speedup vs baseline: 6.8166x; 1.0163x over previous
//
#include <hip/hip_runtime.h>

#define NN 4096

// ws layout (float offsets)
#define OFF_G   0
#define OFF_S   4096
#define OFF_GS  (OFF_S + 64*4096)        // raw-k 32-row group sums [64 heads][128 groups][64]
#define OFF_KP  (OFF_GS + 64*128*64)     // exclusive group prefixes [64][128][64]
#define OFF_W   OFF_GS                   // W = G@S per head [64][64][64] — ALIASES gs (dead after kC)

// ---------------- Kernel A: G = P^T P  (P is [64,64]) ----------------
__global__ void kA_gram(const float* __restrict__ P, float* __restrict__ G) {
    int i = blockIdx.x;      // 0..63
    int j = threadIdx.x;     // 0..63
    float acc = 0.f;
    for (int m = 0; m < 64; ++m)
        acc += P[m*64 + i] * P[m*64 + j];
    G[i*64 + j] = acc;
}

// ------- Kernel B: per (head, 256-row chunk): S += K^T V + raw-k 32-row group sums -------
__launch_bounds__(256)
__global__ void kB(const float* __restrict__ k, const float* __restrict__ v,
                   float* __restrict__ S, float* __restrict__ gs) {
    __shared__ __align__(16) float kt[64*64];   // 16 KB
    __shared__ __align__(16) float vt[64*64];   // 16 KB
    __shared__ float gsb[16*64];                // 16 half-group (16-row) k sums

    int t = threadIdx.x, w = t >> 6, lane = t & 63;
    int head = blockIdx.y, chunk = blockIdx.x;
    long base = ((long)head*NN + (long)chunk*256) * 64;

    float Scol[64];
#pragma unroll
    for (int i = 0; i < 64; ++i) Scol[i] = 0.f;

    for (int s = 0; s < 4; ++s) {
        // stage own 16 rows of k and v (wave-private slice, no barrier needed)
        const float4* kg4 = (const float4*)(k + base + (long)s*4096 + w*1024);
        const float4* vg4 = (const float4*)(v + base + (long)s*4096 + w*1024);
        float4* kl4 = (float4*)&kt[w*1024];
        float4* vl4 = (float4*)&vt[w*1024];
#pragma unroll
        for (int c = 0; c < 4; ++c) {
            kl4[c*64 + lane] = kg4[c*64 + lane];
            vl4[c*64 + lane] = vg4[c*64 + lane];
        }

        // 16-row k half-sum for this wave (feeds the 32-row group sums)
        float hs = 0.f;
#pragma unroll
        for (int r = 0; r < 16; ++r) hs += kt[(w*16 + r)*64 + lane];
        gsb[(s*4 + w)*64 + lane] = hs;

        // S accumulation: Scol[i] += k[r][i] * v[r][lane]
#pragma unroll
        for (int r = 0; r < 16; ++r) {
            float vv = vt[(w*16 + r)*64 + lane];
            const float4* krow = (const float4*)&kt[(w*16 + r)*64];
#pragma unroll
            for (int kq = 0; kq < 16; ++kq) {
                float4 kx = krow[kq];           // wave-uniform broadcast read
                Scol[4*kq+0] += kx.x * vv;
                Scol[4*kq+1] += kx.y * vv;
                Scol[4*kq+2] += kx.z * vv;
                Scol[4*kq+3] += kx.w * vv;
            }
        }
    }
    __syncthreads();

    // gs: combine 16-row halves into 32-row groups (8 groups per chunk)
#pragma unroll
    for (int e = t; e < 512; e += 256) {
        int g = e >> 6, c = e & 63;
        gs[((long)head*128 + chunk*8 + g)*64 + c] = gsb[(2*g)*64 + c] + gsb[(2*g+1)*64 + c];
    }

    // 4-phase cross-wave reduction of Scol into kt, then atomics
    if (w == 0) {
#pragma unroll
        for (int i = 0; i < 64; ++i) kt[i*64 + lane] = Scol[i];
    }
    __syncthreads();
    if (w == 1) {
#pragma unroll
        for (int i = 0; i < 64; ++i) kt[i*64 + lane] += Scol[i];
    }
    __syncthreads();
    if (w == 2) {
#pragma unroll
        for (int i = 0; i < 64; ++i) kt[i*64 + lane] += Scol[i];
    }
    __syncthreads();
    if (w == 3) {
#pragma unroll
        for (int i = 0; i < 64; ++i) kt[i*64 + lane] += Scol[i];
    }
    __syncthreads();
#pragma unroll
    for (int e = t; e < 4096; e += 256)
        atomicAdd(&S[head*4096 + e], kt[e]);
}

// ------- Kernel C: per head: exclusive scan of group sums -> kpre -------
__launch_bounds__(256)
__global__ void kC(const float* __restrict__ gs, float* __restrict__ kpre) {
    __shared__ __align__(16) float gL[128*68];
    int t = threadIdx.x;
    int head = blockIdx.x;

    const float4* gs4 = (const float4*)(gs + (long)head*128*64);
    float4* gL4 = (float4*)gL;
#pragma unroll
    for (int i = 0; i < 8; ++i) {
        int f = t + 256*i;              // 0..2047
        int r = f >> 4, c = f & 15;
        gL4[r*17 + c] = gs4[f];
    }
    __syncthreads();

    if (t < 64) {
        float run = 0.f;
        for (int g = 0; g < 128; ++g) {
            kpre[((long)head*128 + g)*64 + t] = run;
            run += gL[g*68 + t];
        }
    }
}

// ------- Kernel W: per head: W = G @ S  (64x64 @ 64x64) -------
// Runs after kC; writes into the (dead) gs region.
__global__ void kW(const float* __restrict__ G, const float* __restrict__ S,
                   float* __restrict__ W) {
    int i = blockIdx.x;       // output row
    int head = blockIdx.y;
    int j = threadIdx.x;      // output col
    const float* Sh = S + (long)head*4096;
    float acc = 0.f;
#pragma unroll
    for (int m = 0; m < 64; ++m)
        acc = fmaf(G[i*64 + m], Sh[m*64 + j], acc);   // G[i][m] wave-uniform broadcast
    W[(long)head*4096 + i*64 + j] = acc;
}

// ------- Kernel D (fused, LDS-B): acc = q@G, o16 = q@W -------
// Round-3 post-mortem: chunk fences stopped the spill but exposed per-chunk
// GLOBAL B-load latency (VALUBusy 52%). Fix: G and W are block-invariant ->
// stage both into LDS once, per-chunk B fills become lane-consecutive
// ds_read_b32 (conflict-free, low latency). 128-row tiles, 8 waves x 16 rows
// re-amortize B fills over 2048 FMA/wave. Chunk loop stays unroll-1 + fenced
// (round-2 lesson: unfenced fully-unrolled fusion spills ~2.6 KB/thread).
__launch_bounds__(512)
__global__ void kD(const float* __restrict__ q, const float* __restrict__ k,
                   const float* __restrict__ G, const float* __restrict__ W,
                   const float* __restrict__ kpre, float* __restrict__ out) {
    __shared__ __align__(16) float Gs[64*64];     // 16 KB
    __shared__ __align__(16) float Ws[64*64];     // 16 KB
    __shared__ __align__(16) float bufA[128*64];  // 32 KB, q rows (per-wave 16-row slices)

    int t = threadIdx.x, w = t >> 6, lane = t & 63;   // w: 0..7
    int head = blockIdx.y, tile = blockIdx.x;         // 32 tiles of 128 rows
    long rowbase = (long)head*NN + (long)tile*128;    // global row index of tile start

    // ---- cooperative stage G, W -> LDS (coalesced float4; 2 each per thread) ----
    {
        const float4* G4 = (const float4*)G;
        const float4* W4 = (const float4*)(W + (long)head*4096);
        float4* Gs4 = (float4*)Gs;
        float4* Ws4 = (float4*)Ws;
        Gs4[t]       = G4[t];
        Gs4[t + 512] = G4[t + 512];
        Ws4[t]       = W4[t];
        Ws4[t + 512] = W4[t + 512];
    }

    // ---- stage own 16 q rows (wave-private slice) ----
    {
        const float4* qg4 = (const float4*)(q + (rowbase + w*16)*64);
        float4* A4 = (float4*)&bufA[w*1024];
#pragma unroll
        for (int c = 0; c < 4; ++c) A4[c*64 + lane] = qg4[c*64 + lane];
    }
    __syncthreads();   // G/W staging is cross-wave

    float acc[16], o16[16];
#pragma unroll
    for (int r = 0; r < 16; ++r) { acc[r] = 0.f; o16[r] = 0.f; }

    // ---- fused matmul, 4 fenced chunks of 16 columns, B from LDS ----
#pragma unroll 1
    for (int h = 0; h < 4; ++h) {
        __builtin_amdgcn_sched_barrier(0);   // nothing crosses a chunk boundary
        float Gc[16], Wc[16];
#pragma unroll
        for (int kk = 0; kk < 16; ++kk) {
            Gc[kk] = Gs[(h*16 + kk)*64 + lane];   // lane-consecutive, conflict-free
            Wc[kk] = Ws[(h*16 + kk)*64 + lane];
        }
#pragma unroll
        for (int kq = 0; kq < 4; ++kq) {
#pragma unroll
            for (int r = 0; r < 16; ++r) {
                float4 q4 = *(const float4*)&bufA[(w*16 + r)*64 + h*16 + kq*4]; // broadcast
                acc[r] = fmaf(q4.x, Gc[kq*4+0], acc[r]);
                acc[r] = fmaf(q4.y, Gc[kq*4+1], acc[r]);
                acc[r] = fmaf(q4.z, Gc[kq*4+2], acc[r]);
                acc[r] = fmaf(q4.w, Gc[kq*4+3], acc[r]);
                o16[r] = fmaf(q4.x, Wc[kq*4+0], o16[r]);
                o16[r] = fmaf(q4.y, Wc[kq*4+1], o16[r]);
                o16[r] = fmaf(q4.z, Wc[kq*4+2], o16[r]);
                o16[r] = fmaf(q4.w, Wc[kq*4+3], o16[r]);
            }
        }
    }
    __builtin_amdgcn_sched_barrier(0);

    // ---- group prefix: kpre (32-row groups) + odd-wave top-up from global k ----
    // wave rows = [w*16, (w+1)*16); group = tile*4 + (w>>1)
    float pre = kpre[((long)head*128 + tile*4 + (w >> 1))*64 + lane];
    if (w & 1) {
        const float* kp = k + (rowbase + (w-1)*16)*64;
#pragma unroll
        for (int r = 0; r < 16; ++r) pre += kp[r*64 + lane];
    }

    // ---- cumsum (k direct from global, coalesced) + denominators ----
    const float* kown = k + (rowbase + w*16)*64;
    float dinv[16];
#pragma unroll
    for (int r = 0; r < 16; ++r) {
        pre += kown[r*64 + lane];                 // kcum[row][lane]
        float p = acc[r] * pre;                   // qg . kcum, partial per lane
#pragma unroll
        for (int o = 32; o; o >>= 1) p += __shfl_xor(p, o, 64);
        dinv[r] = __builtin_amdgcn_rcpf(p);
    }

    // ---- store ----
#pragma unroll
    for (int r = 0; r < 16; ++r)
        out[(rowbase + w*16 + r)*64 + lane] = o16[r] * dinv[r];
}

extern "C" void kernel_launch(void* const* d_in, const int* in_sizes, int n_in,
                              void* d_out, int out_size, void* d_ws, size_t ws_size,
                              hipStream_t stream) {
    (void)in_sizes; (void)n_in; (void)out_size; (void)ws_size;
    const float* q = (const float*)d_in[0];
    const float* k = (const float*)d_in[1];
    const float* v = (const float*)d_in[2];
    const float* P = (const float*)d_in[3];
    float* out = (float*)d_out;
    float* ws  = (float*)d_ws;

    float* G    = ws + OFF_G;
    float* S    = ws + OFF_S;
    float* gs   = ws + OFF_GS;
    float* kpre = ws + OFF_KP;
    float* W    = ws + OFF_W;     // aliases gs (dead after kC)

    hipMemsetAsync(S, 0, (size_t)64*4096*sizeof(float), stream);
    kA_gram<<<64, 64, 0, stream>>>(P, G);
    kB<<<dim3(16, 64), 256, 0, stream>>>(k, v, S, gs);
    kC<<<64, 256, 0, stream>>>(gs, kpre);
    kW<<<dim3(64, 64), 64, 0, stream>>>(G, S, W);
    kD<<<dim3(32, 64), 512, 0, stream>>>(q, k, G, W, kpre, out);
}